// Round 12
// baseline (727.438 us; speedup 1.0000x reference)
//
#include <hip/hip_runtime.h>
#include <cmath>

namespace {
constexpr int kNZ = 300, kNX = 400;
constexpr int kNPML = 32;
constexpr int kNZP = 364, kNXP = 464;        // padded physical grid
constexpr int kNSTEPS = 200, kNSHOTS = 2;
constexpr int kSRC_Z = 34, kREC_Z = 34;      // NPML + 2
constexpr float kDT = 0.001f;
constexpr float kINV_DX = 100.0f;            // 1/DX

// persistent slabs, 2-step temporal fusion per exchange
constexpr int kR = 4;                         // owned rows per slab
constexpr int kM = 12;                        // extended rows -4..7 (m = row+4)
constexpr int kNSLAB = 92;                    // 368 rows; 364..367 dead (zero moduli)
constexpr int kBlocks = kNSHOTS * kNSLAB;     // 184 blocks, all co-resident
constexpr int kThreads = 512;                 // one column per thread (464 active)
constexpr int kMacro = kNSTEPS / 2;           // 100 exchanges

// LDS: slot pitch 465; col 0 of each slot is a zero guard; data cols 1..464.
// Reading lc+1 at lc=464 lands on the NEXT slot's guard (=0) — exactly the
// reference's zero right-pad. Reading lc-1 at lc=1 hits own guard (=0).
// Slots: A_sxx m=2..10 -> slot m-2 (0..8);  A_sxz m=1..9 -> slot 8+m (9..17)
//        B_vx  m=2..9  -> slot 16+m (18..25); B_vz m=2..9 -> slot 24+m (26..33)
constexpr int kLP = 465;
constexpr int kLDSF = 34 * kLP + 1;           // 15811 floats = 63244 B

// ws: [0,4096) int flags[shot][slab] x16 pad; pub float at 4096:
//   pub[buf][shot][slab][field(5)][row(4)][col(464)]; loss after.
constexpr int kFlagStride = 16;
constexpr long long kPubBase  = 4096;
constexpr long long kPubSlab  = 5LL * kR * kNXP;                    // 9280
constexpr long long kPubCount = 2LL * kNSHOTS * kNSLAB * kPubSlab;  // 3,415,040
constexpr long long kLossOff  = kPubBase + kPubCount;
}  // namespace

__global__ void fwi_init_ws(float* __restrict__ ws) {
    const int gtid = blockIdx.x * blockDim.x + threadIdx.x;
    const int gstride = gridDim.x * blockDim.x;
    for (int q = gtid; q < (int)kPubBase; q += gstride) ws[q] = 0.0f;
    if (gtid == 0) ws[kLossOff] = 0.0f;
}

// Persistent kernel: ONE neighbor exchange per 2 timesteps. Each slab keeps
// exact state on extended rows -4..7 after exchange, then runs 4 phases with
// shrinking validity: V1 (vx m2..10, vz m1..9), S1 (m2..9), V2 (vx m4..8,
// vz m3..7), S2 (m4..7 = owned). Publishes owned 4 rows x 5 fields once
// (parity double-buffer, one flag) for both neighbors.
__global__ __launch_bounds__(kThreads, 1) void fwi_sim_kernel(
    const float* __restrict__ Vp, const float* __restrict__ Vs,
    const float* __restrict__ Den, const float* __restrict__ Stf,
    const int* __restrict__ Shot_ids, float* __restrict__ ws) {
    __shared__ float L[kLDSF];

    const int blk  = blockIdx.x;
    const int s    = blk / kNSLAB;
    const int slab = blk - s * kNSLAB;
    const int r0   = slab * kR;
    const int tid  = threadIdx.x;
    const bool active = tid < kNXP;
    const int lc = tid + 1;

    int*   flags = (int*)ws;
    float* pub   = ws + kPubBase;
    float* lossp = ws + kLossOff;

    for (int q = tid; q < kLDSF; q += kThreads) L[q] = 0.0f;

    // ---- moduli for extended rows (zero outside grid / dead rows) ----
    float rdtr[kM], rdamp[kM], rlam[kM], rmu[kM], rl2m[kM];
#pragma unroll
    for (int m = 0; m < kM; ++m) { rdtr[m]=rdamp[m]=rlam[m]=rmu[m]=rl2m[m]=0.0f; }
    if (active) {
#pragma unroll
        for (int m = 0; m < kM; ++m) {
            const int i = r0 + m - 4;
            const int j = tid;
            if (i >= 0 && i < kNZP) {
                int iz = i - kNPML; iz = iz < 0 ? 0 : (iz > kNZ - 1 ? kNZ - 1 : iz);
                int jx = j - kNPML; jx = jx < 0 ? 0 : (jx > kNX - 1 ? kNX - 1 : jx);
                const float vp  = Vp[iz * kNX + jx];
                const float vs  = Vs[iz * kNX + jx];
                const float rho = Den[iz * kNX + jx];
                const float mm = vs * vs * rho * 1e-6f;
                const float ll = (vp * vp - 2.0f * vs * vs) * rho * 1e-6f;
                const float sc = kDT * kINV_DX;
                float dz = fmaxf((float)(kNPML - i), (float)(i - (kNZP - 1 - kNPML)));
                dz = fminf(fmaxf(dz, 0.0f), (float)kNPML) * (1.0f / kNPML);
                float dxx = fmaxf((float)(kNPML - j), (float)(j - (kNXP - 1 - kNPML)));
                dxx = fminf(fmaxf(dxx, 0.0f), (float)kNPML) * (1.0f / kNPML);
                rdamp[m] = expf(-0.1f * (dz * dz + dxx * dxx));
                rdtr[m]  = kDT / rho * kINV_DX;
                rlam[m]  = ll * sc;
                rmu[m]   = mm * sc;
                rl2m[m]  = (ll + 2.0f * mm) * sc;
            }
        }
    }

    const int id  = Shot_ids[s];
    const int sxp = kNPML + 20 + id * ((kNX - 40) / kNSHOTS);
    const float* stf = Stf + id * kNSTEPS;
    const int msrc = kSRC_Z - r0 + 4;             // extended-row index of source
    const int mrec = kREC_Z - r0 + 4;             // owned only if in [4,7]
    const bool hasRec = (mrec >= 4 && mrec <= 7);
    const float srcm = (active && tid == sxp) ? 1.0f : 0.0f;
    const float recm = (active && (unsigned)(tid - kNPML) < (unsigned)kNX) ? 1.0f : 0.0f;

    const bool hasTop = (slab > 0);
    const bool hasBot = (slab < kNSLAB - 1);
    int* ftopr = hasTop ? &flags[(s * kNSLAB + slab - 1) * kFlagStride] : nullptr;
    int* fbotr = hasBot ? &flags[(s * kNSLAB + slab + 1) * kFlagStride] : nullptr;
    int* fme   = &flags[(s * kNSLAB + slab) * kFlagStride];
    auto pbase = [&](int buf, int sl) {
        return pub + ((long long)(buf * kNSHOTS + s) * kNSLAB + sl) * kPubSlab;
    };

    float fvx[kM] = {}, fvz[kM] = {}, fsxx[kM] = {}, fszz[kM] = {}, fsxz[kM] = {};
    float rsum = 0.0f;
    __syncthreads();

    for (int p = 0; p < kMacro; ++p) {
        // ---- exchange: wait neighbor flags >= p, load ghosts (p=0: zeros) ----
        if (p > 0) {
            if (tid == 0 && hasTop) {
                while (__hip_atomic_load(ftopr, __ATOMIC_RELAXED, __HIP_MEMORY_SCOPE_AGENT) < p) {}
            }
            if (tid == 1 && hasBot) {
                while (__hip_atomic_load(fbotr, __ATOMIC_RELAXED, __HIP_MEMORY_SCOPE_AGENT) < p) {}
            }
            __syncthreads();
            const int rb = (p - 1) & 1;
            if (active && hasTop) {
                const float* b = pbase(rb, slab - 1);
#pragma unroll
                for (int r = 0; r < 4; ++r) {
                    fvx[r]  = __hip_atomic_load(b + (0*4+r)*kNXP + tid, __ATOMIC_RELAXED, __HIP_MEMORY_SCOPE_AGENT);
                    fvz[r]  = __hip_atomic_load(b + (1*4+r)*kNXP + tid, __ATOMIC_RELAXED, __HIP_MEMORY_SCOPE_AGENT);
                    fsxx[r] = __hip_atomic_load(b + (2*4+r)*kNXP + tid, __ATOMIC_RELAXED, __HIP_MEMORY_SCOPE_AGENT);
                    fszz[r] = __hip_atomic_load(b + (3*4+r)*kNXP + tid, __ATOMIC_RELAXED, __HIP_MEMORY_SCOPE_AGENT);
                    fsxz[r] = __hip_atomic_load(b + (4*4+r)*kNXP + tid, __ATOMIC_RELAXED, __HIP_MEMORY_SCOPE_AGENT);
                }
            }
            if (active && hasBot) {
                const float* b = pbase(rb, slab + 1);
#pragma unroll
                for (int r = 0; r < 4; ++r) {
                    fvx[8+r]  = __hip_atomic_load(b + (0*4+r)*kNXP + tid, __ATOMIC_RELAXED, __HIP_MEMORY_SCOPE_AGENT);
                    fvz[8+r]  = __hip_atomic_load(b + (1*4+r)*kNXP + tid, __ATOMIC_RELAXED, __HIP_MEMORY_SCOPE_AGENT);
                    fsxx[8+r] = __hip_atomic_load(b + (2*4+r)*kNXP + tid, __ATOMIC_RELAXED, __HIP_MEMORY_SCOPE_AGENT);
                    fszz[8+r] = __hip_atomic_load(b + (3*4+r)*kNXP + tid, __ATOMIC_RELAXED, __HIP_MEMORY_SCOPE_AGENT);
                    fsxz[8+r] = __hip_atomic_load(b + (4*4+r)*kNXP + tid, __ATOMIC_RELAXED, __HIP_MEMORY_SCOPE_AGENT);
                }
            }
        }

        // ======== V1: velocity step 2p (vx m2..10, vz m1..9) ========
        if (active) {
#pragma unroll
            for (int m = 2; m <= 10; ++m) L[(m-2)*kLP + lc] = fsxx[m];
#pragma unroll
            for (int m = 1; m <= 9; ++m)  L[(8+m)*kLP + lc] = fsxz[m];
        }
        __syncthreads();
        if (active) {
#pragma unroll
            for (int m = 1; m <= 9; ++m) {
                const float sxzL = L[(8+m)*kLP + lc - 1];
                fvz[m] = (fvz[m] + rdtr[m] * ((fsxz[m] - sxzL) + (fszz[m+1] - fszz[m]))) * rdamp[m];
            }
#pragma unroll
            for (int m = 2; m <= 10; ++m) {
                const float sxxR = L[(m-2)*kLP + lc + 1];
                fvx[m] = (fvx[m] + rdtr[m] * ((sxxR - fsxx[m]) + (fsxz[m] - fsxz[m-1]))) * rdamp[m];
            }
            if (hasRec) rsum += recm * fvx[mrec] * fvx[mrec];
        }

        // ======== S1: stress step 2p (m2..9) ========
        if (active) {
#pragma unroll
            for (int m = 2; m <= 9; ++m) { L[(16+m)*kLP + lc] = fvx[m]; L[(24+m)*kLP + lc] = fvz[m]; }
        }
        __syncthreads();
        if (active) {
            const float svalA = stf[2*p] * kDT;
#pragma unroll
            for (int m = 2; m <= 9; ++m) {
                const float vxL = L[(16+m)*kLP + lc - 1];
                const float vzR = L[(24+m)*kLP + lc + 1];
                const float dvx = fvx[m] - vxL;
                const float dvz = fvz[m] - fvz[m-1];
                float nsxx = (fsxx[m] + (rl2m[m]*dvx + rlam[m]*dvz)) * rdamp[m];
                float nszz = (fszz[m] + (rlam[m]*dvx + rl2m[m]*dvz)) * rdamp[m];
                float nsxz = (fsxz[m] + rmu[m]*((fvx[m+1] - fvx[m]) + (vzR - fvz[m]))) * rdamp[m];
                if (m == msrc) { nsxx += srcm * svalA; nszz += srcm * svalA; }
                fsxx[m] = nsxx; fszz[m] = nszz; fsxz[m] = nsxz;
            }
        }

        // ======== V2: velocity step 2p+1 (vx m4..8, vz m3..7) ========
        if (active) {
#pragma unroll
            for (int m = 4; m <= 8; ++m) L[(m-2)*kLP + lc] = fsxx[m];
#pragma unroll
            for (int m = 3; m <= 7; ++m) L[(8+m)*kLP + lc] = fsxz[m];
        }
        __syncthreads();
        if (active) {
#pragma unroll
            for (int m = 3; m <= 7; ++m) {
                const float sxzL = L[(8+m)*kLP + lc - 1];
                fvz[m] = (fvz[m] + rdtr[m] * ((fsxz[m] - sxzL) + (fszz[m+1] - fszz[m]))) * rdamp[m];
            }
#pragma unroll
            for (int m = 4; m <= 8; ++m) {
                const float sxxR = L[(m-2)*kLP + lc + 1];
                fvx[m] = (fvx[m] + rdtr[m] * ((sxxR - fsxx[m]) + (fsxz[m] - fsxz[m-1]))) * rdamp[m];
            }
            if (hasRec) rsum += recm * fvx[mrec] * fvx[mrec];
        }

        // ======== S2: stress step 2p+1 (owned m4..7); publish ========
        if (active) {
#pragma unroll
            for (int m = 4; m <= 7; ++m) { L[(16+m)*kLP + lc] = fvx[m]; L[(24+m)*kLP + lc] = fvz[m]; }
        }
        __syncthreads();
        if (active) {
            const float svalB = stf[2*p+1] * kDT;
#pragma unroll
            for (int m = 4; m <= 7; ++m) {
                const float vxL = L[(16+m)*kLP + lc - 1];
                const float vzR = L[(24+m)*kLP + lc + 1];
                const float dvx = fvx[m] - vxL;
                const float dvz = fvz[m] - fvz[m-1];
                float nsxx = (fsxx[m] + (rl2m[m]*dvx + rlam[m]*dvz)) * rdamp[m];
                float nszz = (fszz[m] + (rlam[m]*dvx + rl2m[m]*dvz)) * rdamp[m];
                float nsxz = (fsxz[m] + rmu[m]*((fvx[m+1] - fvx[m]) + (vzR - fvz[m]))) * rdamp[m];
                if (m == msrc) { nsxx += srcm * svalB; nszz += srcm * svalB; }
                fsxx[m] = nsxx; fszz[m] = nszz; fsxz[m] = nsxz;
            }
            // publish owned rows (m=4..7) once; both neighbors read it
            float* b = pbase(p & 1, slab);
#pragma unroll
            for (int r = 0; r < 4; ++r) {
                __hip_atomic_store(b + (0*4+r)*kNXP + tid, fvx[4+r],  __ATOMIC_RELAXED, __HIP_MEMORY_SCOPE_AGENT);
                __hip_atomic_store(b + (1*4+r)*kNXP + tid, fvz[4+r],  __ATOMIC_RELAXED, __HIP_MEMORY_SCOPE_AGENT);
                __hip_atomic_store(b + (2*4+r)*kNXP + tid, fsxx[4+r], __ATOMIC_RELAXED, __HIP_MEMORY_SCOPE_AGENT);
                __hip_atomic_store(b + (3*4+r)*kNXP + tid, fszz[4+r], __ATOMIC_RELAXED, __HIP_MEMORY_SCOPE_AGENT);
                __hip_atomic_store(b + (4*4+r)*kNXP + tid, fsxz[4+r], __ATOMIC_RELAXED, __HIP_MEMORY_SCOPE_AGENT);
            }
        }
        __syncthreads();   // drains publish stores (vmcnt) before flag
        if (tid == 0) __hip_atomic_store(fme, p + 1, __ATOMIC_RELAXED, __HIP_MEMORY_SCOPE_AGENT);
    }

    for (int off = 32; off > 0; off >>= 1) rsum += __shfl_down(rsum, off, 64);
    if ((tid & 63) == 0 && rsum != 0.0f) atomicAdd(lossp, rsum);
}

__global__ void fwi_finish_kernel(const float* __restrict__ ws,
                                  float* __restrict__ out) {
    out[0] = 0.5f * ws[kLossOff];
}

extern "C" void kernel_launch(void* const* d_in, const int* in_sizes, int n_in,
                              void* d_out, int out_size, void* d_ws, size_t ws_size,
                              hipStream_t stream) {
    const float* Vp  = (const float*)d_in[0];
    const float* Vs  = (const float*)d_in[1];
    const float* Den = (const float*)d_in[2];
    const float* Stf = (const float*)d_in[3];
    // d_in[4] = Mask (all-ones; identity in forward value) -- unused
    const int* Shot_ids = (const int*)d_in[5];
    float* out = (float*)d_out;
    float* ws  = (float*)d_ws;

    fwi_init_ws<<<16, 256, 0, stream>>>(ws);
    void* args[] = {(void*)&Vp, (void*)&Vs, (void*)&Den, (void*)&Stf,
                    (void*)&Shot_ids, (void*)&ws};
    hipLaunchCooperativeKernel((const void*)fwi_sim_kernel, dim3(kBlocks),
                               dim3(kThreads), args, 0, stream);
    fwi_finish_kernel<<<1, 1, 0, stream>>>(ws, out);
}